// Round 15
// baseline (48.294 us; speedup 1.0000x reference)
//
#include <hip/hip_runtime.h>
#include <math.h>

#define BATCH 128
#define NPWM 512
#define LEN 1000
#define NEXT 1024     // 2*NPWM (fwd + revcomp interleaved: f_ext = 2*f + strand)
#define KSLOT 96      // kk padded 19->24, slot = kk*4 + c (16x16x32: K mult of 32)

typedef __bf16 bf16x4 __attribute__((ext_vector_type(4)));
typedef __bf16 bf16x8 __attribute__((ext_vector_type(8)));
typedef float  f32x4  __attribute__((ext_vector_type(4)));

#define MFMA16(a, b, c) __builtin_amdgcn_mfma_f32_16x16x32_bf16(a, b, c, 0, 0, 0)

// ---- prepack W: (512,4,19) fp32 -> (1024,96) bf16 hi/lo, zeros at pad slots ----
__global__ __launch_bounds__(256)
void prepack_w(const float* __restrict__ w, __bf16* __restrict__ whi, __bf16* __restrict__ wlo)
{
    int idx = blockIdx.x * 256 + threadIdx.x;
    if (idx >= NEXT * KSLOT) return;
    int fe = idx / KSLOT;
    int t  = idx - fe * KSLOT;
    int kk = t >> 2;
    int c  = t & 3;
    int f      = fe >> 1;
    int strand = fe & 1;
    float v = 0.0f;
    if (kk < 19)
        v = strand ? w[f*76 + (3-c)*19 + (18-kk)]   // reverse-complement
                   : w[f*76 + c*19 + kk];
    __bf16 h = (__bf16)v;
    whi[idx] = h;
    wlo[idx] = (__bf16)(v - (float)h);
}

// ---- main: 2-term w-split GEMM, 16x16x32, fg=4 (issue-amortized): per iter
// 5 shared b128 B-frags feed 48 MFMAs (4 filter-tiles x 2 pos-tiles x 2 terms
// x 3 k-chunks) in 8 independent dep-6 chains. block = 4 waves = 2 fhalf x
// 2 wp; grid = (128,8); ~176 VGPR -> 2 waves/SIMD, no spill at bounds(256,2).
__global__ __launch_bounds__(256, 2)
void pwm_mfma(const float* __restrict__ x,
              const __bf16* __restrict__ whi,
              const __bf16* __restrict__ wlo,
              float* __restrict__ out)
{
    __shared__ __align__(16) __bf16 S[8256];   // H0 @0, H1 (shifted +1 pos) @4128
    __shared__ float red[2][128];

    const int tid   = threadIdx.x;
    const int b     = blockIdx.x;
    const int ftile = blockIdx.y;   // 0..7 (128 f_ext per block)
    const int lane  = tid & 63;
    const int wave  = tid >> 6;
    const int fhalf = wave & 1;     // which 64 f_ext
    const int wp    = wave >> 1;    // position half
    const int row   = lane & 15;    // position within 16-tile / W k-row
    const int g     = lane >> 4;    // k-eighth group (0..3)

    __bf16* H0 = S;
    __bf16* H1 = S + 4128;          // +32-elem skew (R3): <=3-way read conflicts

    // stage bf16(x[b]) position-major [pos][c] + shifted copy (single pass)
    for (int i = tid; i < 1024; i += 256) {
        bf16x4 hv;
        #pragma unroll
        for (int c = 0; c < 4; ++c) {
            float v = (i < LEN) ? x[(size_t)b*4000 + c*1000 + i] : 0.0f;
            hv[c] = (__bf16)v;
        }
        *(bf16x4*)(H0 + i*4) = hv;
        if (i > 0) *(bf16x4*)(H1 + (i-1)*4) = hv;
    }
    if (tid == 0) { bf16x4 z = {}; *(bf16x4*)(H1 + 1023*4) = z; }

    // A fragments (W hi/lo) -> regs: lane holds W[f0+fg*16+row][k = s*32 + g*8 + j]
    bf16x8 wah[4][3], wal[4][3];
    {
        const int f0 = ftile*128 + fhalf*64;
        #pragma unroll
        for (int fg = 0; fg < 4; ++fg)
            #pragma unroll
            for (int s = 0; s < 3; ++s) {
                const size_t o = (size_t)(f0 + fg*16 + row)*KSLOT + s*32 + g*8;
                wah[fg][s] = *(const bf16x8*)(whi + o);
                wal[fg][s] = *(const bf16x8*)(wlo + o);
            }
    }
    __syncthreads();

    // B base: pos-tile0 pos = it*32 + row; parity(row) loop-invariant -> 16B reads
    const int lp   = row + 2*g;
    const int par  = row & 1;
    const __bf16* bp = par ? H1 : H0;
    const int eoff = lp*4 - (par ? 4 : 0);
    const f32x4 zc = {};

    float m0[4][4], m1[4][4];
    #pragma unroll
    for (int fg = 0; fg < 4; ++fg)
        #pragma unroll
        for (int r = 0; r < 4; ++r) { m0[fg][r] = -INFINITY; m1[fg][r] = -INFINITY; }

    const int it_beg = wp ? 16 : 0;
    const int it_end = wp ? 31 : 16;
    for (int it = it_beg; it < it_end; ++it) {
        const int ibase = it*128 + eoff;
        bf16x8 g0 = *(const bf16x8*)(bp + ibase);
        bf16x8 g1 = *(const bf16x8*)(bp + ibase + 32);
        bf16x8 g2 = *(const bf16x8*)(bp + ibase + 64);   // shared: tile0 s2 / tile1 s0
        bf16x8 g3 = *(const bf16x8*)(bp + ibase + 96);
        bf16x8 g4 = *(const bf16x8*)(bp + ibase + 128);

        f32x4 a0[4], a1[4];   // [fg] chains for pos-tile0 / pos-tile1
        __builtin_amdgcn_s_setprio(1);
        #pragma unroll
        for (int fg = 0; fg < 4; ++fg) {
            a0[fg] = MFMA16(wah[fg][0], g0, zc);
            a1[fg] = MFMA16(wah[fg][0], g2, zc);
        }
        #pragma unroll
        for (int fg = 0; fg < 4; ++fg) {
            a0[fg] = MFMA16(wal[fg][0], g0, a0[fg]);
            a1[fg] = MFMA16(wal[fg][0], g2, a1[fg]);
        }
        #pragma unroll
        for (int fg = 0; fg < 4; ++fg) {
            a0[fg] = MFMA16(wah[fg][1], g1, a0[fg]);
            a1[fg] = MFMA16(wah[fg][1], g3, a1[fg]);
        }
        #pragma unroll
        for (int fg = 0; fg < 4; ++fg) {
            a0[fg] = MFMA16(wal[fg][1], g1, a0[fg]);
            a1[fg] = MFMA16(wal[fg][1], g3, a1[fg]);
        }
        #pragma unroll
        for (int fg = 0; fg < 4; ++fg) {
            a0[fg] = MFMA16(wah[fg][2], g2, a0[fg]);
            a1[fg] = MFMA16(wah[fg][2], g4, a1[fg]);
        }
        #pragma unroll
        for (int fg = 0; fg < 4; ++fg) {
            a0[fg] = MFMA16(wal[fg][2], g2, a0[fg]);
            a1[fg] = MFMA16(wal[fg][2], g4, a1[fg]);
        }
        __builtin_amdgcn_s_setprio(0);

        if (it == 30 && row >= 6) {   // tile1 pos = 976+row >= 982: exclude
            #pragma unroll
            for (int fg = 0; fg < 4; ++fg)
                #pragma unroll
                for (int r = 0; r < 4; ++r) a1[fg][r] = -INFINITY;
        }
        #pragma unroll
        for (int fg = 0; fg < 4; ++fg)
            #pragma unroll
            for (int r = 0; r < 4; ++r) {
                m0[fg][r] = fmaxf(m0[fg][r], a0[fg][r]);
                m1[fg][r] = fmaxf(m1[fg][r], a1[fg][r]);
            }
    }

    // fold pos-tiles then reduce over the 16 position-columns (lane&15)
    #pragma unroll
    for (int fg = 0; fg < 4; ++fg)
        #pragma unroll
        for (int r = 0; r < 4; ++r)
            m0[fg][r] = fmaxf(m0[fg][r], m1[fg][r]);
    #pragma unroll
    for (int off = 1; off < 16; off <<= 1)
        #pragma unroll
        for (int fg = 0; fg < 4; ++fg)
            #pragma unroll
            for (int r = 0; r < 4; ++r)
                m0[fg][r] = fmaxf(m0[fg][r], __shfl_xor(m0[fg][r], off, 64));

    // D row (filter within 16-tile) = g*4 + r
    if (row == 0) {
        #pragma unroll
        for (int fg = 0; fg < 4; ++fg)
            #pragma unroll
            for (int r = 0; r < 4; ++r)
                red[wp][fhalf*64 + fg*16 + g*4 + r] = m0[fg][r];
    }
    __syncthreads();
    if (tid < 64) {   // combine strand pairs (f_ext = 2f, 2f+1) and position halves
        float v0 = fmaxf(red[0][2*tid], red[0][2*tid+1]);
        float v1 = fmaxf(red[1][2*tid], red[1][2*tid+1]);
        out[(size_t)b*NPWM + ftile*64 + tid] = fmaxf(v0, v1);
    }
}

extern "C" void kernel_launch(void* const* d_in, const int* in_sizes, int n_in,
                              void* d_out, int out_size, void* d_ws, size_t ws_size,
                              hipStream_t stream)
{
    const float* x = (const float*)d_in[0];   // (128, 4, 1000)
    const float* w = (const float*)d_in[1];   // (512, 4, 19)
    float* out = (float*)d_out;               // (128, 512)

    __bf16* whi = (__bf16*)d_ws;              // 1024*96 bf16
    __bf16* wlo = whi + NEXT*KSLOT;

    prepack_w<<<dim3((NEXT*KSLOT + 255)/256), 256, 0, stream>>>(w, whi, wlo);
    pwm_mfma<<<dim3(BATCH, 8), 256, 0, stream>>>(x, whi, wlo, out);
}

// Round 16
// 40.472 us; speedup vs baseline: 1.1933x; 1.1933x over previous
//
#include <hip/hip_runtime.h>
#include <math.h>

#define BATCH 128
#define NPWM 512
#define LEN 1000
#define NEXT 1024     // 2*NPWM (fwd + revcomp interleaved: f_ext = 2*f + strand)
#define KSLOT 96      // kk padded 19->24, slot = kk*4 + c (16x16x32: K mult of 32)

typedef __bf16 bf16x4 __attribute__((ext_vector_type(4)));
typedef __bf16 bf16x8 __attribute__((ext_vector_type(8)));
typedef float  f32x4  __attribute__((ext_vector_type(4)));

#define MFMA16(a, b, c) __builtin_amdgcn_mfma_f32_16x16x32_bf16(a, b, c, 0, 0, 0)

// ---- prepack W: (512,4,19) fp32 -> (1024,96) bf16 hi/lo, zeros at pad slots ----
__global__ __launch_bounds__(256)
void prepack_w(const float* __restrict__ w, __bf16* __restrict__ whi, __bf16* __restrict__ wlo)
{
    int idx = blockIdx.x * 256 + threadIdx.x;
    if (idx >= NEXT * KSLOT) return;
    int fe = idx / KSLOT;
    int t  = idx - fe * KSLOT;
    int kk = t >> 2;
    int c  = t & 3;
    int f      = fe >> 1;
    int strand = fe & 1;
    float v = 0.0f;
    if (kk < 19)
        v = strand ? w[f*76 + (3-c)*19 + (18-kk)]   // reverse-complement
                   : w[f*76 + c*19 + kk];
    __bf16 h = (__bf16)v;
    whi[idx] = h;
    wlo[idx] = (__bf16)(v - (float)h);
}

// ---- main: 2-term w-split GEMM, 16x16x32 (R13 structure, trimmed serial work)
// Per iter (2 pos-tiles = 32 pos): 5 shared b128 B-frags feed 20 MFMAs in 4
// independent dep-5 chains. Chunk s=2 (taps 16-18 + pad) computes hi-term only:
// dropping its lo-term adds ~0.007 abs error (12/76 products at 2^-9 rel) and
// cuts pipe work 17%. No setprio: T5 hurts lockstep GEMM loops (m190).
// block = 4 waves x 32 f_ext; grid = (128,8) = 4 blocks/CU.
__global__ __launch_bounds__(256)
void pwm_mfma(const float* __restrict__ x,
              const __bf16* __restrict__ whi,
              const __bf16* __restrict__ wlo,
              float* __restrict__ out)
{
    __shared__ __align__(16) __bf16 S[8256];   // H0 @0, H1 (shifted +1 pos) @4128
    __shared__ float red[128];

    const int tid   = threadIdx.x;
    const int b     = blockIdx.x;
    const int ftile = blockIdx.y;   // 0..7 (128 f_ext per block)
    const int lane  = tid & 63;
    const int wave  = tid >> 6;
    const int row   = lane & 15;    // position within 16-tile / W k-row
    const int g     = lane >> 4;    // k-eighth group (0..3)

    __bf16* H0 = S;
    __bf16* H1 = S + 4128;          // +32-elem skew: odd-parity banks offset (<=3-way)

    // stage bf16(x[b]) position-major [pos][c] + shifted copy (single pass)
    for (int i = tid; i < 1024; i += 256) {
        bf16x4 hv;
        #pragma unroll
        for (int c = 0; c < 4; ++c) {
            float v = (i < LEN) ? x[(size_t)b*4000 + c*1000 + i] : 0.0f;
            hv[c] = (__bf16)v;
        }
        *(bf16x4*)(H0 + i*4) = hv;
        if (i > 0) *(bf16x4*)(H1 + (i-1)*4) = hv;
    }
    if (tid == 0) { bf16x4 z = {}; *(bf16x4*)(H1 + 1023*4) = z; }

    // A fragments (W hi/lo) -> regs: lane holds W[f0+fg*16+row][k = s*32 + g*8 + j]
    // (wal[.][2] never used -> not loaded)
    bf16x8 wah[2][3], wal[2][2];
    {
        const int f0 = ftile*128 + wave*32;
        #pragma unroll
        for (int fg = 0; fg < 2; ++fg) {
            #pragma unroll
            for (int s = 0; s < 3; ++s) {
                const size_t o = (size_t)(f0 + fg*16 + row)*KSLOT + s*32 + g*8;
                wah[fg][s] = *(const bf16x8*)(whi + o);
                if (s < 2) wal[fg][s] = *(const bf16x8*)(wlo + o);
            }
        }
    }
    __syncthreads();

    // B base: pos-tile0 pos = it*32 + row; parity(row) loop-invariant -> 16B reads
    const int lp   = row + 2*g;
    const int par  = row & 1;
    const __bf16* bp = par ? H1 : H0;
    const int eoff = lp*4 - (par ? 4 : 0);

    float m0[4], m1[4];
    #pragma unroll
    for (int r = 0; r < 4; ++r) { m0[r] = -INFINITY; m1[r] = -INFINITY; }
    const f32x4 zc = {};

    for (int it = 0; it < 31; ++it) {
        const int ibase = it*128 + eoff;
        bf16x8 g0 = *(const bf16x8*)(bp + ibase);
        bf16x8 g1 = *(const bf16x8*)(bp + ibase + 32);
        bf16x8 g2 = *(const bf16x8*)(bp + ibase + 64);   // shared: tile0 s2 / tile1 s0
        bf16x8 g3 = *(const bf16x8*)(bp + ibase + 96);
        bf16x8 g4 = *(const bf16x8*)(bp + ibase + 128);

        // 4 independent dep-5 chains (2 filter-tiles x 2 pos-tiles), 20 MFMAs
        f32x4 a00 = MFMA16(wah[0][0], g0, zc);
        f32x4 a10 = MFMA16(wah[1][0], g0, zc);
        f32x4 a01 = MFMA16(wah[0][0], g2, zc);
        f32x4 a11 = MFMA16(wah[1][0], g2, zc);
        a00 = MFMA16(wal[0][0], g0, a00);
        a10 = MFMA16(wal[1][0], g0, a10);
        a01 = MFMA16(wal[0][0], g2, a01);
        a11 = MFMA16(wal[1][0], g2, a11);
        a00 = MFMA16(wah[0][1], g1, a00);
        a10 = MFMA16(wah[1][1], g1, a10);
        a01 = MFMA16(wah[0][1], g3, a01);
        a11 = MFMA16(wah[1][1], g3, a11);
        a00 = MFMA16(wal[0][1], g1, a00);
        a10 = MFMA16(wal[1][1], g1, a10);
        a01 = MFMA16(wal[0][1], g3, a01);
        a11 = MFMA16(wal[1][1], g3, a11);
        a00 = MFMA16(wah[0][2], g2, a00);   // s=2: hi-term only
        a10 = MFMA16(wah[1][2], g2, a10);
        a01 = MFMA16(wah[0][2], g4, a01);
        a11 = MFMA16(wah[1][2], g4, a11);

        if (it == 30 && row >= 6) {   // tile1 pos = 976+row >= 982: exclude
            #pragma unroll
            for (int r = 0; r < 4; ++r) { a01[r] = -INFINITY; a11[r] = -INFINITY; }
        }
        #pragma unroll
        for (int r = 0; r < 4; ++r) {
            m0[r] = fmaxf(m0[r], fmaxf(a00[r], a01[r]));
            m1[r] = fmaxf(m1[r], fmaxf(a10[r], a11[r]));
        }
    }

    // reduce over the 16 position-columns (lane&15)
    #pragma unroll
    for (int off = 1; off < 16; off <<= 1)
        #pragma unroll
        for (int r = 0; r < 4; ++r) {
            m0[r] = fmaxf(m0[r], __shfl_xor(m0[r], off, 64));
            m1[r] = fmaxf(m1[r], __shfl_xor(m1[r], off, 64));
        }

    // D row (filter within 16-tile) = g*4 + r
    if (row == 0) {
        #pragma unroll
        for (int r = 0; r < 4; ++r) {
            red[wave*32 +      g*4 + r] = m0[r];
            red[wave*32 + 16 + g*4 + r] = m1[r];
        }
    }
    __syncthreads();
    if (tid < 64)   // combine strand pairs (f_ext = 2f, 2f+1)
        out[(size_t)b*NPWM + ftile*64 + tid] = fmaxf(red[2*tid], red[2*tid+1]);
}

extern "C" void kernel_launch(void* const* d_in, const int* in_sizes, int n_in,
                              void* d_out, int out_size, void* d_ws, size_t ws_size,
                              hipStream_t stream)
{
    const float* x = (const float*)d_in[0];   // (128, 4, 1000)
    const float* w = (const float*)d_in[1];   // (512, 4, 19)
    float* out = (float*)d_out;               // (128, 512)

    __bf16* whi = (__bf16*)d_ws;              // 1024*96 bf16
    __bf16* wlo = whi + NEXT*KSLOT;

    prepack_w<<<dim3((NEXT*KSLOT + 255)/256), 256, 0, stream>>>(w, whi, wlo);
    pwm_mfma<<<dim3(BATCH, 8), 256, 0, stream>>>(x, whi, wlo, out);
}